// Round 1
// baseline (221254.639 us; speedup 1.0000x reference)
//
#include <hip/hip_runtime.h>
#include <cstdint>
#include <cstddef>

#define SEQ  8192
#define HD   2048
#define IND  16
#define NBLK 256   // one block per CU; each owns 8 hidden units
#define NTHR 512   // 8 waves: wave w -> gate (w>>1), units (w&1)*4..+4

typedef _Float16 h2 __attribute__((ext_vector_type(2)));

__device__ __forceinline__ float fdot2f(h2 a, h2 b, float c) {
#if defined(__has_builtin)
#if __has_builtin(__builtin_amdgcn_fdot2)
    return __builtin_amdgcn_fdot2(a, b, c, false);
#else
    return c + (float)a.x * (float)b.x + (float)a.y * (float)b.y;
#endif
#else
    return c + (float)a.x * (float)b.x + (float)a.y * (float)b.y;
#endif
}

__device__ __forceinline__ float sigmoid_f(float x) {
    return 1.f / (1.f + __expf(-x));
}
__device__ __forceinline__ float tanh_f(float x) {
    // tanh(x) = 1 - 2/(e^{2x}+1); saturates correctly for large |x|
    float e = __expf(2.f * x);
    return 1.f - 2.f / (e + 1.f);
}

// Persistent LSTM kernel: 256 blocks co-resident (1/CU), W_hh held in VGPRs
// as fp16 pairs. Per step: poll per-block ready flags for h_t, stage h_t to
// LDS (fp16, lane-transposed), 64 v_dot2_f32_f16 per thread, cross-lane
// merge-reduce, gate nonlinearities on wave 0, publish h_{t+1} + flag.
__global__ __launch_bounds__(NTHR, 1) void lstm_persist(
    const float* __restrict__ sa,    // [SEQ, IND]
    const float* __restrict__ W_ih,  // [4*HD, IND]
    const float* __restrict__ W_hh,  // [4*HD, HD]
    const float* __restrict__ b_ih,  // [4*HD]
    const float* __restrict__ b_hh,  // [4*HD]
    float* __restrict__ hbuf,        // [2, HD] double buffer (zeroed)
    unsigned* __restrict__ flags,    // [NBLK] steps completed (zeroed)
    _Float16* __restrict__ hs16)     // [SEQ, HD] h history (fp16)
{
    const int b    = blockIdx.x;
    const int tid  = threadIdx.x;
    const int w    = tid >> 6;        // wave 0..7
    const int L    = tid & 63;        // lane
    const int gate = w >> 1;          // 0:i 1:f 2:g 3:o
    const int ub   = (w & 1) * 4;     // unit base within block's 8 units

    __shared__ h2    hh2[16 * 64];    // h_t as fp16 pairs, [pair k][lane]
    __shared__ float sa_s[IND];
    __shared__ float gl[4][8];        // gate pre-activations per unit

    // ---- one-time: W_hh fragment -> registers (fp16 pairs) ----
    // wave handles 4 rows; lane L owns cols [L*32, L*32+32)
    h2 wreg[4][16];
#pragma unroll
    for (int u = 0; u < 4; ++u) {
        const int row = gate * HD + b * 8 + ub + u;
        const float4* Wr = (const float4*)(W_hh + (size_t)row * HD + L * 32);
#pragma unroll
        for (int q = 0; q < 8; ++q) {
            float4 f = Wr[q];
            h2 lo; lo.x = (_Float16)f.x; lo.y = (_Float16)f.y;
            h2 hi; hi.x = (_Float16)f.z; hi.y = (_Float16)f.w;
            wreg[u][2 * q]     = lo;
            wreg[u][2 * q + 1] = hi;
        }
    }
    // W_ih row + bias for the row this lane ends up owning (row = L&3)
    const int rowL = gate * HD + b * 8 + ub + (L & 3);
    float wih[IND];
    {
        const float4* Wi = (const float4*)(W_ih + (size_t)rowL * IND);
#pragma unroll
        for (int q = 0; q < 4; ++q) {
            float4 f = Wi[q];
            wih[4 * q]     = f.x;
            wih[4 * q + 1] = f.y;
            wih[4 * q + 2] = f.z;
            wih[4 * q + 3] = f.w;
        }
    }
    const float bias = b_ih[rowL] + b_hh[rowL];

    float c = 0.f;  // cell state: valid on tid<8 (unit = tid)

    for (unsigned t = 0; t < SEQ; ++t) {
        // ---- A: wait until every block has published h_t ----
        if (tid < NBLK) {
            while (__hip_atomic_load(&flags[tid], __ATOMIC_ACQUIRE,
                                     __HIP_MEMORY_SCOPE_AGENT) < t) { }
        }
        __syncthreads();

        // ---- C: stage h_t into LDS (fp16, transposed pair layout) ----
        {
            const float4 hv4 = *(const float4*)(hbuf + (t & 1) * HD + tid * 4);
            h2 a; a.x = (_Float16)hv4.x; a.y = (_Float16)hv4.y;
            h2 d; d.x = (_Float16)hv4.z; d.y = (_Float16)hv4.w;
            const int p0 = tid * 2, p1 = tid * 2 + 1;
            hh2[(p0 & 15) * 64 + (p0 >> 4)] = a;   // [k][lane] layout:
            hh2[(p1 & 15) * 64 + (p1 >> 4)] = d;   // bank-conflict-free reads
            if (tid < IND) sa_s[tid] = sa[t * IND + tid];
        }
        __syncthreads();

        // ---- E: dot products over this lane's 32 columns ----
        h2 hv[16];
#pragma unroll
        for (int k = 0; k < 16; ++k) hv[k] = hh2[k * 64 + L];
        float p[4] = {0.f, 0.f, 0.f, 0.f};
#pragma unroll
        for (int u = 0; u < 4; ++u)
#pragma unroll
            for (int k = 0; k < 16; ++k)
                p[u] = fdot2f(wreg[u][k], hv[k], p[u]);

        // merge-reduce: end with lane L holding full sum of row (L&3)
        float k0 = (L & 1) ? p[1] : p[0];
        float s0 = (L & 1) ? p[0] : p[1];
        float v0 = k0 + __shfl_xor(s0, 1, 64);
        float k1 = (L & 1) ? p[3] : p[2];
        float s1 = (L & 1) ? p[2] : p[3];
        float v1 = k1 + __shfl_xor(s1, 1, 64);
        float k2 = (L & 2) ? v1 : v0;
        float s2 = (L & 2) ? v0 : v1;
        float tot = k2 + __shfl_xor(s2, 2, 64);
        tot += __shfl_xor(tot, 4, 64);
        tot += __shfl_xor(tot, 8, 64);
        tot += __shfl_xor(tot, 16, 64);
        tot += __shfl_xor(tot, 32, 64);

        // x-projection (input + biases), exact fp32, for row (L&3)
        float xp = bias;
#pragma unroll
        for (int k = 0; k < IND; ++k) xp += sa_s[k] * wih[k];
        tot += xp;

        if (L < 4) gl[gate][ub + L] = tot;
        __syncthreads();

        // ---- H: gate nonlinearities + state update on wave 0 ----
        if (tid < 8) {
            float gi = gl[0][tid], gf = gl[1][tid];
            float gg = gl[2][tid], go = gl[3][tid];
            float ii = sigmoid_f(gi);
            float ff = sigmoid_f(gf);
            float g  = tanh_f(gg);
            float oo = sigmoid_f(go);
            c = ff * c + ii * g;
            float h = oo * tanh_f(c);
            hbuf[((t + 1) & 1) * HD + b * 8 + tid] = h;
            hs16[(size_t)t * HD + b * 8 + tid] = (_Float16)h;
        }
        if (tid == 0) {
            // release orders the wave's hbuf/hs16 stores before the flag
            __hip_atomic_store(&flags[b], t + 1, __ATOMIC_RELEASE,
                               __HIP_MEMORY_SCOPE_AGENT);
        }
    }
}

// Output projection: out[t, 0:3] = hs[t]·W_uvw^T + b_uvw,
//                    out[t, 3:6] = hs[t]·W_pqr^T + b_pqr
// One wave per 4 timesteps; W rows staged in LDS (48 KB).
__global__ __launch_bounds__(256) void out_proj_kernel(
    const _Float16* __restrict__ hs16,
    const float* __restrict__ W_uvw, const float* __restrict__ b_uvw,
    const float* __restrict__ W_pqr, const float* __restrict__ b_pqr,
    float* __restrict__ out)
{
    __shared__ float Ws[6 * HD];
    const int tid = threadIdx.x;
    for (int i = tid; i < 3 * HD; i += 256) Ws[i] = W_uvw[i];
    for (int i = tid; i < 3 * HD; i += 256) Ws[3 * HD + i] = W_pqr[i];
    __syncthreads();

    const int w = tid >> 6, L = tid & 63;
#pragma unroll
    for (int r = 0; r < 4; ++r) {
        const int t = blockIdx.x * 16 + w * 4 + r;
        const _Float16* hrow = hs16 + (size_t)t * HD;
        float acc[6] = {0.f, 0.f, 0.f, 0.f, 0.f, 0.f};
        for (int cidx = L; cidx < HD; cidx += 64) {
            float hval = (float)hrow[cidx];
#pragma unroll
            for (int j = 0; j < 6; ++j) acc[j] += hval * Ws[j * HD + cidx];
        }
#pragma unroll
        for (int j = 0; j < 6; ++j) {
#pragma unroll
            for (int d = 1; d < 64; d <<= 1)
                acc[j] += __shfl_xor(acc[j], d, 64);
        }
        if (L == 0) {
#pragma unroll
            for (int j = 0; j < 6; ++j)
                out[(size_t)t * 6 + j] =
                    acc[j] + (j < 3 ? b_uvw[j] : b_pqr[j - 3]);
        }
    }
}

extern "C" void kernel_launch(void* const* d_in, const int* in_sizes, int n_in,
                              void* d_out, int out_size, void* d_ws, size_t ws_size,
                              hipStream_t stream) {
    (void)in_sizes; (void)n_in; (void)out_size; (void)ws_size;

    const float* sa    = (const float*)d_in[0];
    const float* W_ih  = (const float*)d_in[1];
    const float* W_hh  = (const float*)d_in[2];
    const float* b_ih  = (const float*)d_in[3];
    const float* b_hh  = (const float*)d_in[4];
    const float* W_uvw = (const float*)d_in[5];
    const float* b_uvw = (const float*)d_in[6];
    const float* W_pqr = (const float*)d_in[7];
    const float* b_pqr = (const float*)d_in[8];
    float* out = (float*)d_out;

    // workspace layout: [hs16: SEQ*HD*2 B = 32 MB][hbuf: 2*HD*4 B][flags: NBLK*4 B]
    char* ws = (char*)d_ws;
    _Float16* hs16  = (_Float16*)ws;
    float*    hbuf  = (float*)(ws + (size_t)SEQ * HD * 2);
    unsigned* flags = (unsigned*)(ws + (size_t)SEQ * HD * 2 + (size_t)2 * HD * 4);

    // zero h_0 double buffer + flags (d_ws is poisoned 0xAA before each call)
    hipMemsetAsync(hbuf, 0, (size_t)2 * HD * 4 + (size_t)NBLK * 4, stream);

    hipLaunchKernelGGL(lstm_persist, dim3(NBLK), dim3(NTHR), 0, stream,
                       sa, W_ih, W_hh, b_ih, b_hh, hbuf, flags, hs16);
    hipLaunchKernelGGL(out_proj_kernel, dim3(SEQ / 16), dim3(256), 0, stream,
                       hs16, W_uvw, b_uvw, W_pqr, b_pqr, out);
}

// Round 2
// 23366.174 us; speedup vs baseline: 9.4690x; 9.4690x over previous
//
#include <hip/hip_runtime.h>
#include <cstdint>
#include <cstddef>

#define SEQ  8192
#define HD   2048
#define IND  16
#define NBLK 256   // one block per CU; each owns 8 hidden units
#define NTHR 512   // 8 waves: wave w -> gate (w>>1), units (w&1)*4..+4
#define NPAIR (HD / 2)   // 1024 h2-pair message slots

typedef _Float16 h2 __attribute__((ext_vector_type(2)));

union paircvt { h2 v; unsigned u; };

__device__ __forceinline__ float fdot2f(h2 a, h2 b, float c) {
#if defined(__has_builtin)
#if __has_builtin(__builtin_amdgcn_fdot2)
    return __builtin_amdgcn_fdot2(a, b, c, false);
#else
    return c + (float)a.x * (float)b.x + (float)a.y * (float)b.y;
#endif
#else
    return c + (float)a.x * (float)b.x + (float)a.y * (float)b.y;
#endif
}

__device__ __forceinline__ float sigmoid_f(float x) {
    return 1.f / (1.f + __expf(-x));
}
__device__ __forceinline__ float tanh_f(float x) {
    float e = __expf(2.f * x);
    return 1.f - 2.f / (e + 1.f);
}

// Persistent LSTM. W_hh lives in VGPRs as fp16 pairs (64 VGPR/thread,
// 256 blocks x 512 thr x 64 reg x 4 B = 32 MB = all of W_hh fp16).
//
// Sync protocol (fence-free): h is exchanged as 1024 u64 slots per step
// parity: lo32 = packed 2xfp16 h-pair, hi32 = step tag. Writers publish
// with RELAXED agent-scope atomic stores; readers poll with RELAXED
// agent-scope atomic loads until tag==t. The 8-byte word is atomic, so
// no acquire/release fences (no buffer_inv / buffer_wbl2 per step —
// R1's 27 us/step pathology). Parity double-buffer is safe: a block
// publishes tag t+1 only after consuming every tag t, so no reader can
// still need the slot being overwritten.
__global__ __launch_bounds__(NTHR, 1) void lstm_persist(
    const float* __restrict__ sa,    // [SEQ, IND]
    const float* __restrict__ W_ih,  // [4*HD, IND]
    const float* __restrict__ W_hh,  // [4*HD, HD]
    const float* __restrict__ b_ih,  // [4*HD]
    const float* __restrict__ b_hh,  // [4*HD]
    unsigned long long* __restrict__ hmsg,  // [2][NPAIR] tagged slots (zeroed)
    _Float16* __restrict__ hs16)     // [SEQ, HD] h history (fp16)
{
    const int b    = blockIdx.x;
    const int tid  = threadIdx.x;
    const int w    = tid >> 6;        // wave 0..7
    const int L    = tid & 63;        // lane
    const int gate = w >> 1;          // 0:i 1:f 2:g 3:o
    const int ub   = (w & 1) * 4;     // unit base within block's 8 units

    __shared__ h2    hh2[16 * 64];    // h_t pairs, [k][lane] transposed
    __shared__ float sa_s[IND];
    __shared__ float gl[4][8];        // gate pre-activations per unit

    // ---- one-time: W_hh fragment -> registers (fp16 pairs) ----
    // wave handles 4 rows; lane L owns cols [L*32, L*32+32)
    h2 wreg[4][16];
#pragma unroll
    for (int u = 0; u < 4; ++u) {
        const int row = gate * HD + b * 8 + ub + u;
        const float4* Wr = (const float4*)(W_hh + (size_t)row * HD + L * 32);
#pragma unroll
        for (int q = 0; q < 8; ++q) {
            float4 f = Wr[q];
            h2 lo; lo.x = (_Float16)f.x; lo.y = (_Float16)f.y;
            h2 hi; hi.x = (_Float16)f.z; hi.y = (_Float16)f.w;
            wreg[u][2 * q]     = lo;
            wreg[u][2 * q + 1] = hi;
        }
    }
    // W_ih row + bias for the row lane L (<4) owns
    const int rowL = gate * HD + b * 8 + ub + (L & 3);
    float wih[IND];
    {
        const float4* Wi = (const float4*)(W_ih + (size_t)rowL * IND);
#pragma unroll
        for (int q = 0; q < 4; ++q) {
            float4 f = Wi[q];
            wih[4 * q]     = f.x;
            wih[4 * q + 1] = f.y;
            wih[4 * q + 2] = f.z;
            wih[4 * q + 3] = f.w;
        }
    }
    const float bias = b_ih[rowL] + b_hh[rowL];

    // Message slots this thread polls (contiguous per wave -> coalesced)
    const int p1 = tid;           // pairs [0,512)
    const int p2 = tid + NTHR;    // pairs [512,1024)
    // Cell state: tid<4 owns units 2*tid, 2*tid+1
    float c0 = 0.f, c1 = 0.f;

    for (unsigned t = 0; t < SEQ; ++t) {
        // ---- poll h_t slots (fence-free), stage into LDS ----
        const unsigned long long* mb = hmsg + (size_t)(t & 1) * NPAIR;
        unsigned long long m1, m2;
        for (;;) {
            m1 = __hip_atomic_load(&mb[p1], __ATOMIC_RELAXED,
                                   __HIP_MEMORY_SCOPE_AGENT);
            if ((unsigned)(m1 >> 32) == t) break;
            __builtin_amdgcn_s_sleep(1);
        }
        for (;;) {
            m2 = __hip_atomic_load(&mb[p2], __ATOMIC_RELAXED,
                                   __HIP_MEMORY_SCOPE_AGENT);
            if ((unsigned)(m2 >> 32) == t) break;
            __builtin_amdgcn_s_sleep(1);
        }
        {
            paircvt c1v; c1v.u = (unsigned)m1;
            paircvt c2v; c2v.u = (unsigned)m2;
            hh2[(p1 & 15) * 64 + (p1 >> 4)] = c1v.v;
            hh2[(p2 & 15) * 64 + (p2 >> 4)] = c2v.v;
            if (tid < IND) sa_s[tid] = sa[t * IND + tid];
        }
        __syncthreads();

        // ---- dot products over this lane's 32 columns ----
        h2 hv[16];
#pragma unroll
        for (int k = 0; k < 16; ++k) hv[k] = hh2[k * 64 + L];
        float p[4] = {0.f, 0.f, 0.f, 0.f};
#pragma unroll
        for (int u = 0; u < 4; ++u)
#pragma unroll
            for (int k = 0; k < 16; ++k)
                p[u] = fdot2f(wreg[u][k], hv[k], p[u]);

        // merge-reduce: lane L ends holding full row-sum of row (L&3)
        float k0 = (L & 1) ? p[1] : p[0];
        float s0 = (L & 1) ? p[0] : p[1];
        float v0 = k0 + __shfl_xor(s0, 1, 64);
        float k1 = (L & 1) ? p[3] : p[2];
        float s1 = (L & 1) ? p[2] : p[3];
        float v1 = k1 + __shfl_xor(s1, 1, 64);
        float k2 = (L & 2) ? v1 : v0;
        float s2 = (L & 2) ? v0 : v1;
        float tot = k2 + __shfl_xor(s2, 2, 64);
        tot += __shfl_xor(tot, 4, 64);
        tot += __shfl_xor(tot, 8, 64);
        tot += __shfl_xor(tot, 16, 64);
        tot += __shfl_xor(tot, 32, 64);

        // x-projection (input + biases), fp32, for row (L&3)
        float xp = bias;
#pragma unroll
        for (int k = 0; k < IND; ++k) xp += sa_s[k] * wih[k];
        tot += xp;

        if (L < 4) gl[gate][ub + L] = tot;
        __syncthreads();

        // ---- gates + state update: tid<4 owns units 2*tid, 2*tid+1 ----
        if (tid < 4) {
            const int u0 = 2 * tid, u1 = u0 + 1;
            float i0 = sigmoid_f(gl[0][u0]), i1 = sigmoid_f(gl[0][u1]);
            float f0 = sigmoid_f(gl[1][u0]), f1 = sigmoid_f(gl[1][u1]);
            float g0 = tanh_f(gl[2][u0]),    g1 = tanh_f(gl[2][u1]);
            float o0 = sigmoid_f(gl[3][u0]), o1 = sigmoid_f(gl[3][u1]);
            c0 = f0 * c0 + i0 * g0;
            c1 = f1 * c1 + i1 * g1;
            float h0 = o0 * tanh_f(c0);
            float h1 = o1 * tanh_f(c1);
            paircvt pk;
            pk.v.x = (_Float16)h0;
            pk.v.y = (_Float16)h1;
            // h history (consumed by out_proj after kernel boundary)
            ((unsigned*)hs16)[(size_t)t * (HD / 2) + b * 4 + tid] = pk.u;
            // publish h_{t+1} pair with tag t+1 (fence-free)
            unsigned long long msg =
                ((unsigned long long)(t + 1) << 32) | (unsigned long long)pk.u;
            __hip_atomic_store(&hmsg[(size_t)((t + 1) & 1) * NPAIR + b * 4 + tid],
                               msg, __ATOMIC_RELAXED, __HIP_MEMORY_SCOPE_AGENT);
        }
    }
}

// Output projection: out[t,0:3] = hs[t]·W_uvw^T + b_uvw,
//                    out[t,3:6] = hs[t]·W_pqr^T + b_pqr
__global__ __launch_bounds__(256) void out_proj_kernel(
    const _Float16* __restrict__ hs16,
    const float* __restrict__ W_uvw, const float* __restrict__ b_uvw,
    const float* __restrict__ W_pqr, const float* __restrict__ b_pqr,
    float* __restrict__ out)
{
    __shared__ float Ws[6 * HD];
    const int tid = threadIdx.x;
    for (int i = tid; i < 3 * HD; i += 256) Ws[i] = W_uvw[i];
    for (int i = tid; i < 3 * HD; i += 256) Ws[3 * HD + i] = W_pqr[i];
    __syncthreads();

    const int w = tid >> 6, L = tid & 63;
#pragma unroll
    for (int r = 0; r < 4; ++r) {
        const int t = blockIdx.x * 16 + w * 4 + r;
        const _Float16* hrow = hs16 + (size_t)t * HD;
        float acc[6] = {0.f, 0.f, 0.f, 0.f, 0.f, 0.f};
        for (int cidx = L; cidx < HD; cidx += 64) {
            float hval = (float)hrow[cidx];
#pragma unroll
            for (int j = 0; j < 6; ++j) acc[j] += hval * Ws[j * HD + cidx];
        }
#pragma unroll
        for (int j = 0; j < 6; ++j) {
#pragma unroll
            for (int d = 1; d < 64; d <<= 1)
                acc[j] += __shfl_xor(acc[j], d, 64);
        }
        if (L == 0) {
#pragma unroll
            for (int j = 0; j < 6; ++j)
                out[(size_t)t * 6 + j] =
                    acc[j] + (j < 3 ? b_uvw[j] : b_pqr[j - 3]);
        }
    }
}

extern "C" void kernel_launch(void* const* d_in, const int* in_sizes, int n_in,
                              void* d_out, int out_size, void* d_ws, size_t ws_size,
                              hipStream_t stream) {
    (void)in_sizes; (void)n_in; (void)out_size; (void)ws_size;

    const float* sa    = (const float*)d_in[0];
    const float* W_ih  = (const float*)d_in[1];
    const float* W_hh  = (const float*)d_in[2];
    const float* b_ih  = (const float*)d_in[3];
    const float* b_hh  = (const float*)d_in[4];
    const float* W_uvw = (const float*)d_in[5];
    const float* b_uvw = (const float*)d_in[6];
    const float* W_pqr = (const float*)d_in[7];
    const float* b_pqr = (const float*)d_in[8];
    float* out = (float*)d_out;

    // workspace: [hs16: SEQ*HD*2 B = 32 MB][hmsg: 2*NPAIR*8 B = 16 KB]
    char* ws = (char*)d_ws;
    _Float16* hs16 = (_Float16*)ws;
    unsigned long long* hmsg =
        (unsigned long long*)(ws + (size_t)SEQ * HD * 2);

    // zero tags+values: tag 0 == "h_0 = 0 is ready" for parity-0 buffer
    hipMemsetAsync(hmsg, 0, (size_t)2 * NPAIR * 8, stream);

    hipLaunchKernelGGL(lstm_persist, dim3(NBLK), dim3(NTHR), 0, stream,
                       sa, W_ih, W_hh, b_ih, b_hh, hmsg, hs16);
    hipLaunchKernelGGL(out_proj_kernel, dim3(SEQ / 16), dim3(256), 0, stream,
                       hs16, W_uvw, b_uvw, W_pqr, b_pqr, out);
}